// Round 7
// baseline (98.549 us; speedup 1.0000x reference)
//
#include <hip/hip_runtime.h>

#define N1v 2000
#define N2v 4000
#define DIN 30
#define DZ 32
#define DQ 94
#define INV_TEMP 0.17677669529663687f  // 1/sqrt(32)

__device__ __forceinline__ float wave_reduce_sum(float v) {
#pragma unroll
    for (int off = 32; off; off >>= 1) v += __shfl_xor(v, off, 64);
    return v;
}
__device__ __forceinline__ float wave_reduce_max(float v) {
#pragma unroll
    for (int off = 32; off; off >>= 1) v = fmaxf(v, __shfl_xor(v, off, 64));
    return v;
}

// ---------------------------------------------------------------------------
// Kernel 1: landmark projections (transposed), features, pv, router partials
// ---------------------------------------------------------------------------
__global__ __launch_bounds__(256) void prep_kernel(
    const float* __restrict__ lm_X, const float* __restrict__ lm_Y,
    const float* __restrict__ lm_delay,
    const float* __restrict__ att_kw, const float* __restrict__ att_kb,
    const float* __restrict__ pred_kw, const float* __restrict__ pred_kb,
    const float* __restrict__ pred_vw, const float* __restrict__ pred_vb,
    const float* __restrict__ gamma_1, const float* __restrict__ alpha,
    const float* __restrict__ beta,
    float* __restrict__ lm_feature, float* __restrict__ k_t,
    float* __restrict__ pk_t, float* __restrict__ pv,
    float* __restrict__ pS, float* __restrict__ pW, float* __restrict__ pSd)
{
    __shared__ float sh_x[8][DIN];
    __shared__ float sh_k[DZ][9];
    __shared__ float sh_p[DZ][9];
    __shared__ float sh_s[8][DZ];
    __shared__ float sh_w[8][DZ];
    __shared__ float sh_d[8];
    const int t = threadIdx.x;
    const int base = blockIdx.x * 8;
    if (t < 8 * DIN) sh_x[t / DIN][t % DIN] = lm_X[base * DIN + t];
    __syncthreads();
    const int ty = t >> 5, c = t & 31;
    const int row = base + ty;
    float kacc = att_kb[c], pacc = pred_kb[c];
#pragma unroll
    for (int d = 0; d < DIN; ++d) {
        float x = sh_x[ty][d];
        kacc += x * att_kw[d * DZ + c];
        pacc += x * pred_kw[d * DZ + c];
    }
    sh_k[c][ty] = kacc;
    sh_p[c][ty] = pacc;
    float f = (c < DIN) ? sh_x[ty][c] : lm_Y[row * 2 + (c - DIN)];
    lm_feature[row * DZ + c] = f;
    float ds = __expf(-gamma_1[0] * (alpha[0] * lm_delay[row] + beta[0]));
    sh_s[ty][c] = f;
    sh_w[ty][c] = ds * f;
    if (c == 0) sh_d[ty] = ds;
    if (c < 2) {
        pv[row * 2 + c] = lm_Y[row * 2] * pred_vw[c] +
                          lm_Y[row * 2 + 1] * pred_vw[2 + c] + pred_vb[c];
    }
    __syncthreads();
    const int oc = t >> 3, orow = t & 7;   // transpose store: k_t[32][2000]
    k_t[oc * N1v + base + orow] = sh_k[oc][orow];
    pk_t[oc * N1v + base + orow] = sh_p[oc][orow];
    if (t < DZ) {
        float S = 0.f, W = 0.f;
#pragma unroll
        for (int g = 0; g < 8; ++g) { S += sh_s[g][t]; W += sh_w[g][t]; }
        pS[blockIdx.x * DZ + t] = S;
        pW[blockIdx.x * DZ + t] = W;
    }
    if (t == DZ) {
        float Sd = 0.f;
#pragma unroll
        for (int g = 0; g < 8; ++g) Sd += sh_d[g];
        pSd[blockIdx.x] = Sd;
    }
}

// ---------------------------------------------------------------------------
// Kernel 2: reduce 250 partials -> router_0, router_1 (tiny)
// ---------------------------------------------------------------------------
__global__ __launch_bounds__(256) void router_kernel(
    const float* __restrict__ pS, const float* __restrict__ pW,
    const float* __restrict__ pSd,
    const float* __restrict__ w1_w, const float* __restrict__ w1_b,
    float* __restrict__ router_0, float* __restrict__ router_1)
{
    __shared__ float ps[8][DZ];
    __shared__ float pw[8][DZ];
    __shared__ float pd[8];
    __shared__ float hr[DZ];
    const int t = threadIdx.x;
    const int c = t & 31, g = t >> 5;
    float S = 0.f, W = 0.f, Sd = 0.f;
    for (int b = g; b < 250; b += 8) {
        S += pS[b * DZ + c];
        W += pW[b * DZ + c];
        if (c == 0) Sd += pSd[b];
    }
    ps[g][c] = S;
    pw[g][c] = W;
    if (c == 0) pd[g] = Sd;
    __syncthreads();
    if (t < DZ) {
        float S2 = 0.f, W2 = 0.f, Sd2 = 0.f;
#pragma unroll
        for (int g2 = 0; g2 < 8; ++g2) { S2 += ps[g2][t]; W2 += pw[g2][t]; Sd2 += pd[g2]; }
        float r0 = S2 / (float)N1v;
        router_0[t] = r0;
        hr[t] = (r0 + W2) / (1.f + Sd2);
    }
    __syncthreads();
    if (t < DZ) {
        float acc = w1_b[t];
#pragma unroll
        for (int d = 0; d < DZ; ++d) acc += hr[d] * w1_w[d * DZ + t];
        router_1[t] = acc;
    }
}

// ---------------------------------------------------------------------------
// Kernel 3a: attention 1 + graph steps + pq projection (stored to ws).
// Block = 8 waves (512 thr) = 4 targets; wave w owns landmark tile w (one
// 256-row tile -> plain softmax per wave, no online rescale). One barrier,
// 8-way log-sum-exp merge; graph phase split across waves 0 and 1.
// Grid = 1000 -> 8000 waves (round-6 was 2000 waves, 17% occupancy).
// ---------------------------------------------------------------------------
__global__ __launch_bounds__(512) void attn1_kernel(
    const float* __restrict__ tg_X, const float* __restrict__ tg_delay,
    const float* __restrict__ att_qw, const float* __restrict__ att_qb,
    const float* __restrict__ w1_w, const float* __restrict__ w1_b,
    const float* __restrict__ w2_w, const float* __restrict__ w2_b,
    const float* __restrict__ pred_qw, const float* __restrict__ pred_qb,
    const float* __restrict__ gamma_2, const float* __restrict__ gamma_3,
    const float* __restrict__ alpha, const float* __restrict__ beta,
    const float* __restrict__ k_t, const float* __restrict__ lm_feature,
    const float* __restrict__ router_0, const float* __restrict__ router_1,
    float* __restrict__ ftf_out, float* __restrict__ pq_ws)
{
    __shared__ __align__(16) float e_lds[8][4][256];   // [wave][tgt][lm] 32KB
    __shared__ __align__(16) float xagg[8][4][DZ];     // [wave][tgt][ch] 4KB
    __shared__ float2 xmd[8][4];                       // [wave][tgt] {m,den}
    const int wv = threadIdx.x >> 6;
    const int lane = threadIdx.x & 63;
    const int half = lane >> 5, c = lane & 31;
    const int i0 = blockIdx.x * 4;

    float xA = (c < DIN) ? tg_X[(i0 + half) * DIN + c] : 0.f;
    float xB = (c < DIN) ? tg_X[(i0 + 2 + half) * DIN + c] : 0.f;

    // ---- q projection (redundant per wave; cheap) ----
    float qA = att_qb[c], qB = qA;
#pragma unroll 8
    for (int d = 0; d < DIN; ++d) {
        float w = att_qw[d * DZ + c];
        qA += (half ? __shfl(xA, 32 + d, 64) : __shfl(xA, d, 64)) * w;
        qB += (half ? __shfl(xB, 32 + d, 64) : __shfl(xB, d, 64)) * w;
    }
    qA *= INV_TEMP; qB *= INV_TEMP;

    const int r0 = lane * 4;
    const int rg = lane >> 3, cq = lane & 7;

    // ---- one tile per wave: scores ----
    const int tb = wv << 8;
    const int j = tb + r0;
    const int rld = (j <= N1v - 4) ? j : (N1v - 4);
    const bool dead = (j >= N1v);
    float s[4][4] = {{0,0,0,0},{0,0,0,0},{0,0,0,0},{0,0,0,0}};
    const float* kp = k_t + rld;
#pragma unroll 4
    for (int cc = 0; cc < DZ; ++cc) {
        float4 kt = *(const float4*)(kp + cc * N1v);
        float q0 = __shfl(qA, cc, 64), q1 = __shfl(qA, 32 + cc, 64);
        float q2 = __shfl(qB, cc, 64), q3 = __shfl(qB, 32 + cc, 64);
        s[0][0] += q0*kt.x; s[0][1] += q0*kt.y; s[0][2] += q0*kt.z; s[0][3] += q0*kt.w;
        s[1][0] += q1*kt.x; s[1][1] += q1*kt.y; s[1][2] += q1*kt.z; s[1][3] += q1*kt.w;
        s[2][0] += q2*kt.x; s[2][1] += q2*kt.y; s[2][2] += q2*kt.z; s[2][3] += q2*kt.w;
        s[3][0] += q3*kt.x; s[3][1] += q3*kt.y; s[3][2] += q3*kt.z; s[3][3] += q3*kt.w;
    }
    if (dead) {
#pragma unroll
        for (int mt = 0; mt < 4; ++mt)
#pragma unroll
            for (int k = 0; k < 4; ++k) s[mt][k] = -1e30f;
    }
    float m[4], den[4];
#pragma unroll
    for (int mt = 0; mt < 4; ++mt) {
        float tmax = fmaxf(fmaxf(s[mt][0], s[mt][1]), fmaxf(s[mt][2], s[mt][3]));
        m[mt] = wave_reduce_max(tmax);
        float e0 = __expf(s[mt][0] - m[mt]), e1 = __expf(s[mt][1] - m[mt]);
        float e2 = __expf(s[mt][2] - m[mt]), e3 = __expf(s[mt][3] - m[mt]);
        den[mt] = (e0 + e1) + (e2 + e3);
        float4 ev = {e0, e1, e2, e3};
        *(float4*)&e_lds[wv][mt][r0] = ev;   // wave-private; DS pipe in-order
    }

    // ---- weighted feature aggregation (coalesced, 8 rows/iter) ----
    float agg[4][4] = {{0,0,0,0},{0,0,0,0},{0,0,0,0},{0,0,0,0}};
    const int pmax = (wv == 7) ? 26 : 32;   // tile 7: 208 valid rows
    const float* lmp = lm_feature + (tb + rg) * DZ + cq * 4;
#pragma unroll 2
    for (int p = 0; p < pmax; ++p) {
        float4 lmv = *(const float4*)(lmp + (p << 3) * DZ);
        int jj = (p << 3) + rg;
        float e0 = e_lds[wv][0][jj], e1 = e_lds[wv][1][jj];
        float e2 = e_lds[wv][2][jj], e3 = e_lds[wv][3][jj];
        agg[0][0] += e0*lmv.x; agg[0][1] += e0*lmv.y; agg[0][2] += e0*lmv.z; agg[0][3] += e0*lmv.w;
        agg[1][0] += e1*lmv.x; agg[1][1] += e1*lmv.y; agg[1][2] += e1*lmv.z; agg[1][3] += e1*lmv.w;
        agg[2][0] += e2*lmv.x; agg[2][1] += e2*lmv.y; agg[2][2] += e2*lmv.z; agg[2][3] += e2*lmv.w;
        agg[3][0] += e3*lmv.x; agg[3][1] += e3*lmv.y; agg[3][2] += e3*lmv.z; agg[3][3] += e3*lmv.w;
    }
#pragma unroll
    for (int mt = 0; mt < 4; ++mt) {
#pragma unroll
        for (int off = 8; off <= 32; off <<= 1)
#pragma unroll
            for (int k = 0; k < 4; ++k) agg[mt][k] += __shfl_xor(agg[mt][k], off, 64);
        den[mt] = wave_reduce_sum(den[mt]);
    }
    if (lane < 8) {
#pragma unroll
        for (int mt = 0; mt < 4; ++mt) {
            float4 av = {agg[mt][0], agg[mt][1], agg[mt][2], agg[mt][3]};
            *(float4*)&xagg[wv][mt][lane * 4] = av;
        }
    }
    if (lane == 0) {
#pragma unroll
        for (int mt = 0; mt < 4; ++mt) xmd[wv][mt] = make_float2(m[mt], den[mt]);
    }
    __syncthreads();
    if (wv >= 2) return;

    // ---- 8-way merge + graph steps + pq (wave 0: tp=0, wave 1: tp=1) ----
    const float al = alpha[0], be = beta[0];
    const float g2 = gamma_2[0], g3 = gamma_3[0];
    const int tp = wv;
    const int tt = tp * 2 + half;
    const int i = i0 + tt;
    float M = -1e30f;
#pragma unroll
    for (int w = 0; w < 8; ++w) M = fmaxf(M, xmd[w][tt].x);
    float dsum = 0.f, asum = 0.f;
#pragma unroll
    for (int w = 0; w < 8; ++w) {
        float2 md = xmd[w][tt];
        float scw = __expf(md.x - M);
        dsum += scw * md.y;
        asum += scw * xagg[w][tt][c];
    }
    float td = tg_delay[i];
    float r2t0 = __expf(-g2 * (al * td + be));
    float r2t1 = __expf(-g3 * (al * td + be));
    float xr = tp ? xB : xA;
    float h0 = (xr + asum / dsum + r2t0 * router_0[c]) / (2.f + r2t0);
    float tf1 = w1_b[c];
#pragma unroll 8
    for (int d = 0; d < DZ; ++d)
        tf1 += (half ? __shfl(h0, 32 + d, 64) : __shfl(h0, d, 64)) * w1_w[d * DZ + c];
    float h1 = (tf1 + r2t1 * router_1[c]) / (1.f + r2t1);
    float tf2 = w2_b[c];
#pragma unroll 8
    for (int d = 0; d < DZ; ++d)
        tf2 += (half ? __shfl(h1, 32 + d, 64) : __shfl(h1, d, 64)) * w2_w[d * DZ + c];
    if (c < DIN) ftf_out[i * DQ + c] = xr;
    ftf_out[i * DQ + DIN + c] = tf1;
    ftf_out[i * DQ + DIN + DZ + c] = tf2;
    float pq = pred_qb[c];
#pragma unroll 8
    for (int d = 0; d < DIN; ++d)
        pq += (half ? __shfl(xr, 32 + d, 64) : __shfl(xr, d, 64)) * pred_qw[d * DZ + c];
#pragma unroll 8
    for (int d = 0; d < DZ; ++d)
        pq += (half ? __shfl(tf1, 32 + d, 64) : __shfl(tf1, d, 64)) * pred_qw[(DIN + d) * DZ + c];
#pragma unroll 8
    for (int d = 0; d < DZ; ++d)
        pq += (half ? __shfl(tf2, 32 + d, 64) : __shfl(tf2, d, 64)) * pred_qw[(DIN + DZ + d) * DZ + c];
    pq_ws[i * DZ + c] = pq * INV_TEMP;
}

// ---------------------------------------------------------------------------
// Kernel 3b: attention 2. Same 8-wave/4-target decomposition; all-register
// pv aggregation; one barrier + 8-way merge by wave 0.
// ---------------------------------------------------------------------------
__global__ __launch_bounds__(512) void attn2_kernel(
    const float* __restrict__ pq_ws, const float* __restrict__ pk_t,
    const float* __restrict__ pv, float* __restrict__ y_out)
{
    __shared__ float4 x2[8][4];   // [wave][tgt] {m,den,y0,y1}
    const int wv = threadIdx.x >> 6;
    const int lane = threadIdx.x & 63;
    const int half = lane >> 5, c = lane & 31;
    const int i0 = blockIdx.x * 4;

    float qA = pq_ws[(i0 + half) * DZ + c];
    float qB = pq_ws[(i0 + 2 + half) * DZ + c];

    const int r0 = lane * 4;
    const int tb = wv << 8;
    const int j = tb + r0;
    const int rld = (j <= N1v - 4) ? j : (N1v - 4);
    const bool dead = (j >= N1v);
    float s[4][4] = {{0,0,0,0},{0,0,0,0},{0,0,0,0},{0,0,0,0}};
    const float* kp = pk_t + rld;
#pragma unroll 4
    for (int cc = 0; cc < DZ; ++cc) {
        float4 kt = *(const float4*)(kp + cc * N1v);
        float q0 = __shfl(qA, cc, 64), q1 = __shfl(qA, 32 + cc, 64);
        float q2 = __shfl(qB, cc, 64), q3 = __shfl(qB, 32 + cc, 64);
        s[0][0] += q0*kt.x; s[0][1] += q0*kt.y; s[0][2] += q0*kt.z; s[0][3] += q0*kt.w;
        s[1][0] += q1*kt.x; s[1][1] += q1*kt.y; s[1][2] += q1*kt.z; s[1][3] += q1*kt.w;
        s[2][0] += q2*kt.x; s[2][1] += q2*kt.y; s[2][2] += q2*kt.z; s[2][3] += q2*kt.w;
        s[3][0] += q3*kt.x; s[3][1] += q3*kt.y; s[3][2] += q3*kt.z; s[3][3] += q3*kt.w;
    }
    if (dead) {
#pragma unroll
        for (int mt = 0; mt < 4; ++mt)
#pragma unroll
            for (int k = 0; k < 4; ++k) s[mt][k] = -1e30f;
    }
    float4 pva = *(const float4*)(pv + 2 * rld);
    float4 pvb = *(const float4*)(pv + 2 * rld + 4);
#pragma unroll
    for (int mt = 0; mt < 4; ++mt) {
        float tmax = fmaxf(fmaxf(s[mt][0], s[mt][1]), fmaxf(s[mt][2], s[mt][3]));
        float nm = wave_reduce_max(tmax);
        float e0 = __expf(s[mt][0] - nm), e1 = __expf(s[mt][1] - nm);
        float e2 = __expf(s[mt][2] - nm), e3 = __expf(s[mt][3] - nm);
        float d2 = (e0 + e1) + (e2 + e3);
        float ya = e0*pva.x + e1*pva.z + e2*pvb.x + e3*pvb.z;
        float yb = e0*pva.y + e1*pva.w + e2*pvb.y + e3*pvb.w;
        d2 = wave_reduce_sum(d2);
        ya = wave_reduce_sum(ya);
        yb = wave_reduce_sum(yb);
        if (lane == 0) x2[wv][mt] = make_float4(nm, d2, ya, yb);
    }
    __syncthreads();
    if (wv == 0 && lane < 4) {
        const int mt = lane;
        float M = -1e30f;
#pragma unroll
        for (int w = 0; w < 8; ++w) M = fmaxf(M, x2[w][mt].x);
        float D = 0.f, Y0 = 0.f, Y1 = 0.f;
#pragma unroll
        for (int w = 0; w < 8; ++w) {
            float4 v = x2[w][mt];
            float scw = __expf(v.x - M);
            D += scw * v.y; Y0 += scw * v.z; Y1 += scw * v.w;
        }
        y_out[2 * (i0 + mt)] = Y0 / D;
        y_out[2 * (i0 + mt) + 1] = Y1 / D;
    }
}

extern "C" void kernel_launch(void* const* d_in, const int* in_sizes, int n_in,
                              void* d_out, int out_size, void* d_ws, size_t ws_size,
                              hipStream_t stream) {
    const float* lm_X     = (const float*)d_in[0];
    const float* lm_Y     = (const float*)d_in[1];
    const float* tg_X     = (const float*)d_in[2];
    const float* lm_delay = (const float*)d_in[4];
    const float* tg_delay = (const float*)d_in[5];
    const float* gamma_1  = (const float*)d_in[6];
    const float* gamma_2  = (const float*)d_in[7];
    const float* gamma_3  = (const float*)d_in[8];
    const float* alpha    = (const float*)d_in[9];
    const float* beta     = (const float*)d_in[10];
    const float* att_qw   = (const float*)d_in[11];
    const float* att_qb   = (const float*)d_in[12];
    const float* att_kw   = (const float*)d_in[13];
    const float* att_kb   = (const float*)d_in[14];
    const float* w1_w     = (const float*)d_in[17];
    const float* w1_b     = (const float*)d_in[18];
    const float* w2_w     = (const float*)d_in[19];
    const float* w2_b     = (const float*)d_in[20];
    const float* pred_qw  = (const float*)d_in[21];
    const float* pred_qb  = (const float*)d_in[22];
    const float* pred_kw  = (const float*)d_in[23];
    const float* pred_kb  = (const float*)d_in[24];
    const float* pred_vw  = (const float*)d_in[25];
    const float* pred_vb  = (const float*)d_in[26];

    float* ws          = (float*)d_ws;
    float* k_t         = ws;             // 32 x 2000
    float* pk_t        = ws + 64000;     // 32 x 2000
    float* lm_feature  = ws + 128000;    // 2000 x 32
    float* pv          = ws + 192000;    // 2000 x 2
    float* pS          = ws + 196000;    // 250 x 32
    float* pW          = ws + 204000;    // 250 x 32
    float* pSd         = ws + 212000;    // 250 (+pad)
    float* router_0    = ws + 212256;    // 32
    float* router_1    = ws + 212288;    // 32
    float* pq_ws       = ws + 212320;    // 4000 x 32

    float* y_out   = (float*)d_out;      // 4000 x 2
    float* ftf_out = y_out + 2 * N2v;    // 4000 x 94

    prep_kernel<<<N1v / 8, 256, 0, stream>>>(
        lm_X, lm_Y, lm_delay, att_kw, att_kb, pred_kw, pred_kb,
        pred_vw, pred_vb, gamma_1, alpha, beta,
        lm_feature, k_t, pk_t, pv, pS, pW, pSd);

    router_kernel<<<1, 256, 0, stream>>>(
        pS, pW, pSd, w1_w, w1_b, router_0, router_1);

    attn1_kernel<<<N2v / 4, 512, 0, stream>>>(
        tg_X, tg_delay, att_qw, att_qb, w1_w, w1_b, w2_w, w2_b,
        pred_qw, pred_qb, gamma_2, gamma_3, alpha, beta,
        k_t, lm_feature, router_0, router_1, ftf_out, pq_ws);

    attn2_kernel<<<N2v / 4, 512, 0, stream>>>(
        pq_ws, pk_t, pv, y_out);
}

// Round 8
// 90.819 us; speedup vs baseline: 1.0851x; 1.0851x over previous
//
#include <hip/hip_runtime.h>

#define N1v 2000
#define N2v 4000
#define DIN 30
#define DZ 32
#define DQ 94
#define INV_TEMP 0.17677669529663687f  // 1/sqrt(32)

__device__ __forceinline__ float wave_reduce_sum(float v) {
#pragma unroll
    for (int off = 32; off; off >>= 1) v += __shfl_xor(v, off, 64);
    return v;
}
__device__ __forceinline__ float wave_reduce_max(float v) {
#pragma unroll
    for (int off = 32; off; off >>= 1) v = fmaxf(v, __shfl_xor(v, off, 64));
    return v;
}
// uniform-lane broadcast via v_readlane (VALU/SGPR path, NO DS pipe)
__device__ __forceinline__ float rlane(float v, int l) {
    return __uint_as_float(__builtin_amdgcn_readlane(__float_as_uint(v), l));
}

// ---------------------------------------------------------------------------
// Kernel 1: blocks 0..249: landmark projections (transposed), features, pv,
// router partials. Blocks 250..749: target q projection (hoisted out of attn1
// — round 7 showed per-wave redundant q-projection shfls loading the DS pipe).
// ---------------------------------------------------------------------------
__global__ __launch_bounds__(256) void prep_kernel(
    const float* __restrict__ lm_X, const float* __restrict__ lm_Y,
    const float* __restrict__ lm_delay, const float* __restrict__ tg_X,
    const float* __restrict__ att_qw, const float* __restrict__ att_qb,
    const float* __restrict__ att_kw, const float* __restrict__ att_kb,
    const float* __restrict__ pred_kw, const float* __restrict__ pred_kb,
    const float* __restrict__ pred_vw, const float* __restrict__ pred_vb,
    const float* __restrict__ gamma_1, const float* __restrict__ alpha,
    const float* __restrict__ beta,
    float* __restrict__ lm_feature, float* __restrict__ k_t,
    float* __restrict__ pk_t, float* __restrict__ pv,
    float* __restrict__ pS, float* __restrict__ pW, float* __restrict__ pSd,
    float* __restrict__ q_ws)
{
    __shared__ float sh_x[8][DIN];
    __shared__ float sh_k[DZ][9];
    __shared__ float sh_p[DZ][9];
    __shared__ float sh_s[8][DZ];
    __shared__ float sh_w[8][DZ];
    __shared__ float sh_d[8];
    const int t = threadIdx.x;

    if (blockIdx.x >= 250) {          // ---- target q projection ----
        const int base = (blockIdx.x - 250) * 8;
        if (t < 8 * DIN) sh_x[t / DIN][t % DIN] = tg_X[base * DIN + t];
        __syncthreads();
        const int ty = t >> 5, c2 = t & 31;
        float acc = att_qb[c2];
#pragma unroll
        for (int d = 0; d < DIN; ++d) acc += sh_x[ty][d] * att_qw[d * DZ + c2];
        q_ws[(base + ty) * DZ + c2] = acc * INV_TEMP;
        return;
    }

    const int base = blockIdx.x * 8;
    if (t < 8 * DIN) sh_x[t / DIN][t % DIN] = lm_X[base * DIN + t];
    __syncthreads();
    const int ty = t >> 5, c = t & 31;
    const int row = base + ty;
    float kacc = att_kb[c], pacc = pred_kb[c];
#pragma unroll
    for (int d = 0; d < DIN; ++d) {
        float x = sh_x[ty][d];
        kacc += x * att_kw[d * DZ + c];
        pacc += x * pred_kw[d * DZ + c];
    }
    sh_k[c][ty] = kacc;
    sh_p[c][ty] = pacc;
    float f = (c < DIN) ? sh_x[ty][c] : lm_Y[row * 2 + (c - DIN)];
    lm_feature[row * DZ + c] = f;
    float ds = __expf(-gamma_1[0] * (alpha[0] * lm_delay[row] + beta[0]));
    sh_s[ty][c] = f;
    sh_w[ty][c] = ds * f;
    if (c == 0) sh_d[ty] = ds;
    if (c < 2) {
        pv[row * 2 + c] = lm_Y[row * 2] * pred_vw[c] +
                          lm_Y[row * 2 + 1] * pred_vw[2 + c] + pred_vb[c];
    }
    __syncthreads();
    const int oc = t >> 3, orow = t & 7;   // transpose store: k_t[32][2000]
    k_t[oc * N1v + base + orow] = sh_k[oc][orow];
    pk_t[oc * N1v + base + orow] = sh_p[oc][orow];
    if (t < DZ) {
        float S = 0.f, W = 0.f;
#pragma unroll
        for (int g = 0; g < 8; ++g) { S += sh_s[g][t]; W += sh_w[g][t]; }
        pS[blockIdx.x * DZ + t] = S;
        pW[blockIdx.x * DZ + t] = W;
    }
    if (t == DZ) {
        float Sd = 0.f;
#pragma unroll
        for (int g = 0; g < 8; ++g) Sd += sh_d[g];
        pSd[blockIdx.x] = Sd;
    }
}

// ---------------------------------------------------------------------------
// Kernel 2: reduce 250 partials -> router_0, router_1 (tiny)
// ---------------------------------------------------------------------------
__global__ __launch_bounds__(256) void router_kernel(
    const float* __restrict__ pS, const float* __restrict__ pW,
    const float* __restrict__ pSd,
    const float* __restrict__ w1_w, const float* __restrict__ w1_b,
    float* __restrict__ router_0, float* __restrict__ router_1)
{
    __shared__ float ps[8][DZ];
    __shared__ float pw[8][DZ];
    __shared__ float pd[8];
    __shared__ float hr[DZ];
    const int t = threadIdx.x;
    const int c = t & 31, g = t >> 5;
    float S = 0.f, W = 0.f, Sd = 0.f;
    for (int b = g; b < 250; b += 8) {
        S += pS[b * DZ + c];
        W += pW[b * DZ + c];
        if (c == 0) Sd += pSd[b];
    }
    ps[g][c] = S;
    pw[g][c] = W;
    if (c == 0) pd[g] = Sd;
    __syncthreads();
    if (t < DZ) {
        float S2 = 0.f, W2 = 0.f, Sd2 = 0.f;
#pragma unroll
        for (int g2 = 0; g2 < 8; ++g2) { S2 += ps[g2][t]; W2 += pw[g2][t]; Sd2 += pd[g2]; }
        float r0 = S2 / (float)N1v;
        router_0[t] = r0;
        hr[t] = (r0 + W2) / (1.f + Sd2);
    }
    __syncthreads();
    if (t < DZ) {
        float acc = w1_b[t];
#pragma unroll
        for (int d = 0; d < DZ; ++d) acc += hr[d] * w1_w[d * DZ + t];
        router_1[t] = acc;
    }
}

// ---------------------------------------------------------------------------
// Kernel 3a: attention 1 + graph + pq. 8 waves x 4 targets/block, grid 1000.
// DS-diet vs round 7: q preloaded (no projection shfls); score broadcast via
// v_readlane (no ds_bpermute); e stored TRANSPOSED in LDS
// (pos=(r&7)*36+(r>>3), conflict-free) so agg reads are 16 ds_read_b128
// instead of 128 ds_read_b32. LDS 22.8KB -> 4 blocks/CU.
// ---------------------------------------------------------------------------
__global__ __launch_bounds__(512) void attn1_kernel(
    const float* __restrict__ tg_X, const float* __restrict__ tg_delay,
    const float* __restrict__ q_ws,
    const float* __restrict__ w1_w, const float* __restrict__ w1_b,
    const float* __restrict__ w2_w, const float* __restrict__ w2_b,
    const float* __restrict__ pred_qw, const float* __restrict__ pred_qb,
    const float* __restrict__ gamma_2, const float* __restrict__ gamma_3,
    const float* __restrict__ alpha, const float* __restrict__ beta,
    const float* __restrict__ k_t, const float* __restrict__ lm_feature,
    const float* __restrict__ router_0, const float* __restrict__ router_1,
    float* __restrict__ ftf_out, float* __restrict__ pq_ws)
{
    __shared__ __align__(16) float e_lds[8][2][288];   // 18.4KB, transposed e
    __shared__ __align__(16) float xagg[8][4][DZ];     // 4KB
    __shared__ float2 xmd[8][4];                       // 256B
    const int wv = threadIdx.x >> 6;
    const int lane = threadIdx.x & 63;
    const int half = lane >> 5, c = lane & 31;
    const int i0 = blockIdx.x * 4;

    float qA = q_ws[(i0 + half) * DZ + c];
    float qB = q_ws[(i0 + 2 + half) * DZ + c];

    const int r0 = lane * 4;
    const int tb = wv << 8;
    const int j = tb + r0;
    const int rld = (j <= N1v - 4) ? j : (N1v - 4);
    const bool dead = (j >= N1v);
    const int rg = lane >> 3, cq = lane & 7;
    const int wbase = (r0 & 7) * 36 + (r0 >> 3);  // transposed e write base
    const int ebase = rg * 36;                    // transposed e read base

#pragma unroll 1
    for (int pass = 0; pass < 2; ++pass) {
        const float qP = pass ? qB : qA;
        float s[2][4] = {{0,0,0,0},{0,0,0,0}};
        const float* kp = k_t + rld;
#pragma unroll 8
        for (int cc = 0; cc < DZ; ++cc) {
            float4 kt = *(const float4*)(kp + cc * N1v);
            float q0 = rlane(qP, cc);
            float q1 = rlane(qP, 32 + cc);
            s[0][0] += q0*kt.x; s[0][1] += q0*kt.y; s[0][2] += q0*kt.z; s[0][3] += q0*kt.w;
            s[1][0] += q1*kt.x; s[1][1] += q1*kt.y; s[1][2] += q1*kt.z; s[1][3] += q1*kt.w;
        }
        if (dead) {
#pragma unroll
            for (int mt = 0; mt < 2; ++mt)
#pragma unroll
                for (int k = 0; k < 4; ++k) s[mt][k] = -1e30f;
        }
        float m[2], den[2];
#pragma unroll
        for (int mt = 0; mt < 2; ++mt) {
            float tmax = fmaxf(fmaxf(s[mt][0], s[mt][1]), fmaxf(s[mt][2], s[mt][3]));
            float nm = wave_reduce_max(tmax);
            m[mt] = nm;
            float e0 = __expf(s[mt][0] - nm), e1 = __expf(s[mt][1] - nm);
            float e2 = __expf(s[mt][2] - nm), e3 = __expf(s[mt][3] - nm);
            den[mt] = (e0 + e1) + (e2 + e3);
            e_lds[wv][mt][wbase      ] = e0;   // 2-lane/bank: free
            e_lds[wv][mt][wbase +  36] = e1;
            e_lds[wv][mt][wbase +  72] = e2;
            e_lds[wv][mt][wbase + 108] = e3;
        }
        float agg[2][4] = {{0,0,0,0},{0,0,0,0}};
        const float* lmp = lm_feature + (tb + rg) * DZ + cq * 4;
#pragma unroll 2
        for (int p4 = 0; p4 < 8; ++p4) {
            float4 e0v = *(const float4*)&e_lds[wv][0][ebase + p4 * 4];
            float4 e1v = *(const float4*)&e_lds[wv][1][ebase + p4 * 4];
#pragma unroll
            for (int k = 0; k < 4; ++k) {
                float4 lmv = *(const float4*)(lmp + ((p4 * 4 + k) << 8));
                float e0 = (k == 0) ? e0v.x : (k == 1) ? e0v.y : (k == 2) ? e0v.z : e0v.w;
                float e1 = (k == 0) ? e1v.x : (k == 1) ? e1v.y : (k == 2) ? e1v.z : e1v.w;
                agg[0][0] += e0*lmv.x; agg[0][1] += e0*lmv.y; agg[0][2] += e0*lmv.z; agg[0][3] += e0*lmv.w;
                agg[1][0] += e1*lmv.x; agg[1][1] += e1*lmv.y; agg[1][2] += e1*lmv.z; agg[1][3] += e1*lmv.w;
            }
        }
        // reduce across the 8 row-groups (xor 8/16/32), den across lanes
#pragma unroll
        for (int mt = 0; mt < 2; ++mt) {
#pragma unroll
            for (int off = 8; off <= 32; off <<= 1)
#pragma unroll
                for (int k = 0; k < 4; ++k) agg[mt][k] += __shfl_xor(agg[mt][k], off, 64);
            den[mt] = wave_reduce_sum(den[mt]);
        }
        if (lane < 8) {
#pragma unroll
            for (int mt = 0; mt < 2; ++mt) {
                float4 av = {agg[mt][0], agg[mt][1], agg[mt][2], agg[mt][3]};
                *(float4*)&xagg[wv][pass * 2 + mt][lane * 4] = av;
            }
        }
        if (lane == 0) {
#pragma unroll
            for (int mt = 0; mt < 2; ++mt)
                xmd[wv][pass * 2 + mt] = make_float2(m[mt], den[mt]);
        }
    }
    __syncthreads();
    if (wv >= 2) return;

    // ---- 8-way merge + graph steps + pq (waves 0,1; readlane matvecs) ----
    const float al = alpha[0], be = beta[0];
    const float g2v = gamma_2[0], g3v = gamma_3[0];
    const int tt = wv * 2 + half;
    const int i = i0 + tt;
    float xr = (c < DIN) ? tg_X[i * DIN + c] : 0.f;
    float M = -1e30f;
#pragma unroll
    for (int w = 0; w < 8; ++w) M = fmaxf(M, xmd[w][tt].x);
    float dsum = 0.f, asum = 0.f;
#pragma unroll
    for (int w = 0; w < 8; ++w) {
        float2 md = xmd[w][tt];
        float scw = __expf(md.x - M);
        dsum += scw * md.y;
        asum += scw * xagg[w][tt][c];
    }
    float td = tg_delay[i];
    float r2t0 = __expf(-g2v * (al * td + be));
    float r2t1 = __expf(-g3v * (al * td + be));
    float h0 = (xr + asum / dsum + r2t0 * router_0[c]) / (2.f + r2t0);
    float tf1 = w1_b[c];
#pragma unroll 8
    for (int d = 0; d < DZ; ++d) {
        float hv = half ? rlane(h0, 32 + d) : rlane(h0, d);
        tf1 += hv * w1_w[d * DZ + c];
    }
    float h1 = (tf1 + r2t1 * router_1[c]) / (1.f + r2t1);
    float tf2 = w2_b[c];
#pragma unroll 8
    for (int d = 0; d < DZ; ++d) {
        float hv = half ? rlane(h1, 32 + d) : rlane(h1, d);
        tf2 += hv * w2_w[d * DZ + c];
    }
    if (c < DIN) ftf_out[i * DQ + c] = xr;
    ftf_out[i * DQ + DIN + c] = tf1;
    ftf_out[i * DQ + DIN + DZ + c] = tf2;
    float pq = pred_qb[c];
#pragma unroll 8
    for (int d = 0; d < DIN; ++d) {
        float hv = half ? rlane(xr, 32 + d) : rlane(xr, d);
        pq += hv * pred_qw[d * DZ + c];
    }
#pragma unroll 8
    for (int d = 0; d < DZ; ++d) {
        float hv = half ? rlane(tf1, 32 + d) : rlane(tf1, d);
        pq += hv * pred_qw[(DIN + d) * DZ + c];
    }
#pragma unroll 8
    for (int d = 0; d < DZ; ++d) {
        float hv = half ? rlane(tf2, 32 + d) : rlane(tf2, d);
        pq += hv * pred_qw[(DIN + DZ + d) * DZ + c];
    }
    pq_ws[i * DZ + c] = pq * INV_TEMP;
}

// ---------------------------------------------------------------------------
// Kernel 3b: attention 2. 8 waves x 4 targets, readlane broadcasts,
// all-register pv aggregation; one barrier + 8-way merge.
// ---------------------------------------------------------------------------
__global__ __launch_bounds__(512) void attn2_kernel(
    const float* __restrict__ pq_ws, const float* __restrict__ pk_t,
    const float* __restrict__ pv, float* __restrict__ y_out)
{
    __shared__ float4 x2[8][4];
    const int wv = threadIdx.x >> 6;
    const int lane = threadIdx.x & 63;
    const int half = lane >> 5, c = lane & 31;
    const int i0 = blockIdx.x * 4;

    float qA = pq_ws[(i0 + half) * DZ + c];
    float qB = pq_ws[(i0 + 2 + half) * DZ + c];

    const int r0 = lane * 4;
    const int tb = wv << 8;
    const int j = tb + r0;
    const int rld = (j <= N1v - 4) ? j : (N1v - 4);
    const bool dead = (j >= N1v);
    float s[4][4] = {{0,0,0,0},{0,0,0,0},{0,0,0,0},{0,0,0,0}};
    const float* kp = pk_t + rld;
#pragma unroll 8
    for (int cc = 0; cc < DZ; ++cc) {
        float4 kt = *(const float4*)(kp + cc * N1v);
        float q0 = rlane(qA, cc), q1 = rlane(qA, 32 + cc);
        float q2 = rlane(qB, cc), q3 = rlane(qB, 32 + cc);
        s[0][0] += q0*kt.x; s[0][1] += q0*kt.y; s[0][2] += q0*kt.z; s[0][3] += q0*kt.w;
        s[1][0] += q1*kt.x; s[1][1] += q1*kt.y; s[1][2] += q1*kt.z; s[1][3] += q1*kt.w;
        s[2][0] += q2*kt.x; s[2][1] += q2*kt.y; s[2][2] += q2*kt.z; s[2][3] += q2*kt.w;
        s[3][0] += q3*kt.x; s[3][1] += q3*kt.y; s[3][2] += q3*kt.z; s[3][3] += q3*kt.w;
    }
    if (dead) {
#pragma unroll
        for (int mt = 0; mt < 4; ++mt)
#pragma unroll
            for (int k = 0; k < 4; ++k) s[mt][k] = -1e30f;
    }
    float4 pva = *(const float4*)(pv + 2 * rld);
    float4 pvb = *(const float4*)(pv + 2 * rld + 4);
#pragma unroll
    for (int mt = 0; mt < 4; ++mt) {
        float tmax = fmaxf(fmaxf(s[mt][0], s[mt][1]), fmaxf(s[mt][2], s[mt][3]));
        float nm = wave_reduce_max(tmax);
        float e0 = __expf(s[mt][0] - nm), e1 = __expf(s[mt][1] - nm);
        float e2 = __expf(s[mt][2] - nm), e3 = __expf(s[mt][3] - nm);
        float d2 = (e0 + e1) + (e2 + e3);
        float ya = e0*pva.x + e1*pva.z + e2*pvb.x + e3*pvb.z;
        float yb = e0*pva.y + e1*pva.w + e2*pvb.y + e3*pvb.w;
        d2 = wave_reduce_sum(d2);
        ya = wave_reduce_sum(ya);
        yb = wave_reduce_sum(yb);
        if (lane == 0) x2[wv][mt] = make_float4(nm, d2, ya, yb);
    }
    __syncthreads();
    if (wv == 0 && lane < 4) {
        const int mt = lane;
        float M = -1e30f;
#pragma unroll
        for (int w = 0; w < 8; ++w) M = fmaxf(M, x2[w][mt].x);
        float D = 0.f, Y0 = 0.f, Y1 = 0.f;
#pragma unroll
        for (int w = 0; w < 8; ++w) {
            float4 v = x2[w][mt];
            float scw = __expf(v.x - M);
            D += scw * v.y; Y0 += scw * v.z; Y1 += scw * v.w;
        }
        y_out[2 * (i0 + mt)] = Y0 / D;
        y_out[2 * (i0 + mt) + 1] = Y1 / D;
    }
}

extern "C" void kernel_launch(void* const* d_in, const int* in_sizes, int n_in,
                              void* d_out, int out_size, void* d_ws, size_t ws_size,
                              hipStream_t stream) {
    const float* lm_X     = (const float*)d_in[0];
    const float* lm_Y     = (const float*)d_in[1];
    const float* tg_X     = (const float*)d_in[2];
    const float* lm_delay = (const float*)d_in[4];
    const float* tg_delay = (const float*)d_in[5];
    const float* gamma_1  = (const float*)d_in[6];
    const float* gamma_2  = (const float*)d_in[7];
    const float* gamma_3  = (const float*)d_in[8];
    const float* alpha    = (const float*)d_in[9];
    const float* beta     = (const float*)d_in[10];
    const float* att_qw   = (const float*)d_in[11];
    const float* att_qb   = (const float*)d_in[12];
    const float* att_kw   = (const float*)d_in[13];
    const float* att_kb   = (const float*)d_in[14];
    const float* w1_w     = (const float*)d_in[17];
    const float* w1_b     = (const float*)d_in[18];
    const float* w2_w     = (const float*)d_in[19];
    const float* w2_b     = (const float*)d_in[20];
    const float* pred_qw  = (const float*)d_in[21];
    const float* pred_qb  = (const float*)d_in[22];
    const float* pred_kw  = (const float*)d_in[23];
    const float* pred_kb  = (const float*)d_in[24];
    const float* pred_vw  = (const float*)d_in[25];
    const float* pred_vb  = (const float*)d_in[26];

    float* ws          = (float*)d_ws;
    float* k_t         = ws;             // 32 x 2000
    float* pk_t        = ws + 64000;     // 32 x 2000
    float* lm_feature  = ws + 128000;    // 2000 x 32
    float* pv          = ws + 192000;    // 2000 x 2
    float* pS          = ws + 196000;    // 250 x 32
    float* pW          = ws + 204000;    // 250 x 32
    float* pSd         = ws + 212000;    // 250 (+pad)
    float* router_0    = ws + 212256;    // 32
    float* router_1    = ws + 212288;    // 32
    float* pq_ws       = ws + 212320;    // 4000 x 32
    float* q_ws        = ws + 340320;    // 4000 x 32

    float* y_out   = (float*)d_out;      // 4000 x 2
    float* ftf_out = y_out + 2 * N2v;    // 4000 x 94

    prep_kernel<<<250 + N2v / 8, 256, 0, stream>>>(
        lm_X, lm_Y, lm_delay, tg_X, att_qw, att_qb, att_kw, att_kb,
        pred_kw, pred_kb, pred_vw, pred_vb, gamma_1, alpha, beta,
        lm_feature, k_t, pk_t, pv, pS, pW, pSd, q_ws);

    router_kernel<<<1, 256, 0, stream>>>(
        pS, pW, pSd, w1_w, w1_b, router_0, router_1);

    attn1_kernel<<<N2v / 4, 512, 0, stream>>>(
        tg_X, tg_delay, q_ws, w1_w, w1_b, w2_w, w2_b,
        pred_qw, pred_qb, gamma_2, gamma_3, alpha, beta,
        k_t, lm_feature, router_0, router_1, ftf_out, pq_ws);

    attn2_kernel<<<N2v / 4, 512, 0, stream>>>(
        pq_ws, pk_t, pv, y_out);
}